// Round 10
// baseline (555.565 us; speedup 1.0000x reference)
//
#include <hip/hip_runtime.h>
#include <hip/hip_bf16.h>

#define N_NODES 8000
#define D_IN    2048
#define NE      100000
#define NQUADS  16000000          // N_NODES*N_NODES/4
#define SCAN_BLOCKS 2048
#define NSEG    8192              // SCAN_BLOCKS*256/64 waves
#define SEG_CAP 240

typedef __attribute__((ext_vector_type(8))) short bf16x8;
typedef __attribute__((ext_vector_type(4))) float f32x4;

__device__ inline unsigned short f2bf(float f) {
  union { float f; unsigned u; } v; v.f = f;
  unsigned r = v.u + 0x7fffu + ((v.u >> 16) & 1u);   // round-to-nearest-even
  return (unsigned short)(r >> 16);
}

// ---- pack W_pb/W_nb into transposed bf16 [256 cols][2048 k] ---------------
__global__ void packw_kernel(const float* __restrict__ Wpb,
                             const float* __restrict__ Wnb,
                             unsigned short* __restrict__ WT) {
  int idx = blockIdx.x * 256 + threadIdx.x;   // = c*2048 + k
  int c = idx >> 11;
  int k = idx & 2047;
  const float* W = (c < 128) ? Wpb : Wnb;
  int cc = c & 63;
  int kk = (c & 64) ? (2048 + k) : k;
  WT[idx] = f2bf(W[(size_t)kk * 64 + cc]);
}

// ---- GEMM1 (fused cast, 2-deep A prefetch): Y = bf16(X) @ Wpack -----------
__global__ void gemm1_kernel(const float* __restrict__ X,
                             const unsigned short* __restrict__ WT,
                             float* __restrict__ Y) {
  int wave = threadIdx.x >> 6;
  int lane = threadIdx.x & 63;
  int lrow = lane & 15;
  int koff = (lane >> 4) * 8;
  int row = blockIdx.x * 16 + lrow;
  int col0 = wave * 64;
  f32x4 acc[4] = {};
  const float* Ap = X + (size_t)row * D_IN + koff;
  const unsigned short* Bp = WT + (size_t)(col0 + lrow) * D_IN + koff;
  f32x4 a0 = *reinterpret_cast<const f32x4*>(Ap);
  f32x4 a1 = *reinterpret_cast<const f32x4*>(Ap + 4);
  for (int k0 = 0; k0 < D_IN; k0 += 32) {
    f32x4 n0, n1;
    if (k0 + 32 < D_IN) {
      n0 = *reinterpret_cast<const f32x4*>(Ap + k0 + 32);
      n1 = *reinterpret_cast<const f32x4*>(Ap + k0 + 36);
    }
    bf16x8 af;
    af[0] = (short)f2bf(a0.x); af[1] = (short)f2bf(a0.y);
    af[2] = (short)f2bf(a0.z); af[3] = (short)f2bf(a0.w);
    af[4] = (short)f2bf(a1.x); af[5] = (short)f2bf(a1.y);
    af[6] = (short)f2bf(a1.z); af[7] = (short)f2bf(a1.w);
#pragma unroll
    for (int c = 0; c < 4; ++c) {
      bf16x8 b = *reinterpret_cast<const bf16x8*>(Bp + (size_t)c * 16 * D_IN + k0);
      acc[c] = __builtin_amdgcn_mfma_f32_16x16x32_bf16(af, b, acc[c], 0, 0, 0);
    }
    a0 = n0; a1 = n1;
  }
  int crow = blockIdx.x * 16 + (lane >> 4) * 4;
  int ccol = col0 + (lane & 15);
#pragma unroll
  for (int c = 0; c < 4; ++c)
#pragma unroll
    for (int r = 0; r < 4; ++r)
      Y[(size_t)(crow + r) * 256 + ccol + c * 16] = acc[c][r];
}

// ---- CSR build: count -> scan -> fill -------------------------------------
__global__ void count_kernel(const int* __restrict__ pe, const int* __restrict__ ne,
                             int* __restrict__ cntP, int* __restrict__ cntN) {
  int e = blockIdx.x * 256 + threadIdx.x;
  if (e < NE) atomicAdd(&cntP[pe[e]], 1);
  else if (e < 2 * NE) atomicAdd(&cntN[ne[e - NE]], 1);
}

__global__ void scan_kernel(const int* __restrict__ cntP, const int* __restrict__ cntN,
                            int* __restrict__ rpP, int* __restrict__ rpN) {
  const int* cnt = blockIdx.x ? cntN : cntP;
  int* rp = blockIdx.x ? rpN : rpP;
  __shared__ int s[1024];
  int t = threadIdx.x;
  int base = t * 8;
  int loc[8]; int tot = 0;
#pragma unroll
  for (int i = 0; i < 8; ++i) {
    int v = (base + i < N_NODES) ? cnt[base + i] : 0;
    loc[i] = tot; tot += v;
  }
  s[t] = tot; __syncthreads();
  for (int off = 1; off < 1024; off <<= 1) {
    int v = (t >= off) ? s[t - off] : 0;
    __syncthreads();
    s[t] += v;
    __syncthreads();
  }
  int pre = t ? s[t - 1] : 0;
#pragma unroll
  for (int i = 0; i < 8; ++i) {
    int idx = base + i;
    if (idx <= N_NODES) rp[idx] = pre + loc[i];
  }
}

__global__ void fill_kernel(const int* __restrict__ pe, const int* __restrict__ ne,
                            const int* __restrict__ rpP, const int* __restrict__ rpN,
                            int* __restrict__ curP, int* __restrict__ curN,
                            int* __restrict__ colP, int* __restrict__ colN) {
  int e = blockIdx.x * 256 + threadIdx.x;
  if (e < NE) {
    int r = pe[e];
    int pos = atomicAdd(&curP[r], 1);
    colP[rpP[r] + pos] = pe[NE + e];
  } else if (e < 2 * NE) {
    int ee = e - NE;
    int r = ne[ee];
    int pos = atomicAdd(&curN[r], 1);
    colN[rpN[r] + pos] = ne[NE + ee];
  }
}

// ---- base (pull): mean-agg + self + bias, l2norm, tanh -> H1 ---------------
__global__ void base_kernel(const float* __restrict__ Y,
                            const int* __restrict__ rpP, const int* __restrict__ colP,
                            const int* __restrict__ rpN, const int* __restrict__ colN,
                            const float* __restrict__ bpb, const float* __restrict__ bnb,
                            float* __restrict__ H1) {
  int n = blockIdx.x;
  int w = threadIdx.x >> 6;   // 0 = pos, 1 = neg
  int d = threadIdx.x & 63;
  const int* rp = w ? rpN : rpP;
  const int* ci = w ? colN : colP;
  int s0 = rp[n], e0 = rp[n + 1];
  int off = w ? 128 : 0;
  float sum = 0.0f;
  for (int i = s0; i < e0; ++i) sum += Y[(size_t)ci[i] * 256 + off + d];
  float pre = sum / fmaxf((float)(e0 - s0), 1.0f)
            + Y[(size_t)n * 256 + off + 64 + d] + (w ? bnb : bpb)[d];
  float ss = pre * pre;
#pragma unroll
  for (int o = 32; o > 0; o >>= 1) ss += __shfl_xor(ss, o);
  H1[(size_t)n * 128 + w * 64 + d] = tanhf(pre / fmaxf(sqrtf(ss), 1e-12f));
}

// ---- deep (pull): mean-agg + GEMV + l2norm + tanh + final norm -------------
__global__ void deep_kernel(const float* __restrict__ H1,
                            const int* __restrict__ rpP, const int* __restrict__ colP,
                            const int* __restrict__ rpN, const int* __restrict__ colN,
                            const float* __restrict__ Wpd, const float* __restrict__ bpd,
                            const float* __restrict__ Wnd, const float* __restrict__ bnd,
                            float* __restrict__ Xmol, float* __restrict__ XmolWS) {
  int n = blockIdx.x;
  int t = threadIdx.x;          // 0..127 ; wave0 computes h_pos2, wave1 h_neg2
  int w = t >> 6;
  int lane = t & 63;
  __shared__ float sh_op[128], sh_on[128], sh_h[128], sh_ss[2];
  int sP = rpP[n], eP = rpP[n + 1];
  int sN = rpN[n], eN = rpN[n + 1];
  float sp = 0.0f, sn = 0.0f;
  for (int i = sP; i < eP; ++i) sp += H1[(size_t)colP[i] * 128 + t];
  for (int i = sN; i < eN; ++i) sn += H1[(size_t)colN[i] * 128 + t];
  float hv = H1[(size_t)n * 128 + t];
  sh_h[t]  = hv;
  sh_op[t] = (sp + hv) / (float)(eP - sP + 1);   // mean incl. self-loop
  sh_on[t] = (sn + hv) / (float)(eN - sN + 1);
  __syncthreads();
  const float* W = w ? Wnd : Wpd;
  float pre = (w ? bnd : bpd)[lane];
  int o1b = w ? 64 : 0;
  int o2b = w ? 0 : 64;
  for (int k = 0; k < 64; ++k) pre += sh_op[o1b + k] * W[k * 64 + lane];
  for (int k = 0; k < 64; ++k) pre += sh_on[o2b + k] * W[(64 + k) * 64 + lane];
  for (int k = 0; k < 64; ++k) pre += sh_h[w * 64 + k] * W[(128 + k) * 64 + lane];
  float ss = pre * pre;
#pragma unroll
  for (int o = 32; o > 0; o >>= 1) ss += __shfl_xor(ss, o);
  float tv = tanhf(pre / fmaxf(sqrtf(ss), 1e-12f));
  float ts = tv * tv;
#pragma unroll
  for (int o = 32; o > 0; o >>= 1) ts += __shfl_xor(ts, o);
  if (lane == 0) sh_ss[w] = ts;
  __syncthreads();
  float xm = tv / fmaxf(sqrtf(sh_ss[0] + sh_ss[1]), 1e-12f);
  Xmol[(size_t)n * 128 + t] = xm;
  XmolWS[(size_t)n * 128 + t] = xm;
}

// ---- mask_scan: stream mask+labels, zero pred, Sum(label^2), compact hits --
// per-wave private segments: NO allocation atomics.
__global__ void mask_scan_kernel(const float* __restrict__ mask,
                                 const float* __restrict__ labels,
                                 float* __restrict__ pred,
                                 uint2* __restrict__ entries,
                                 int* __restrict__ wave_count,
                                 float* __restrict__ lossAcc) {
  int tid = blockIdx.x * 256 + threadIdx.x;
  int lane = threadIdx.x & 63;
  int wid = tid >> 6;
  uint2* seg = entries + (size_t)wid * SEG_CAP;
  int lcount = 0;
  float lsum = 0.0f;
  const int stride = SCAN_BLOCKS * 256;
  f32x4 zero4 = {0.0f, 0.0f, 0.0f, 0.0f};
  for (unsigned q = tid; q < NQUADS; q += stride) {
    f32x4 m = *reinterpret_cast<const f32x4*>(mask + (size_t)q * 4);
    f32x4 l = *reinterpret_cast<const f32x4*>(labels + (size_t)q * 4);
    *reinterpret_cast<f32x4*>(pred + (size_t)q * 4) = zero4;
    lsum += l.x * l.x + l.y * l.y + l.z * l.z + l.w * l.w;
#pragma unroll
    for (int c = 0; c < 4; ++c) {
      float mv = (c == 0) ? m.x : (c == 1) ? m.y : (c == 2) ? m.z : m.w;
      float lv = (c == 0) ? l.x : (c == 1) ? l.y : (c == 2) ? l.z : l.w;
      unsigned long long bal = __ballot(mv != 0.0f);
      if (bal) {
        if (mv != 0.0f) {
          int rank = __popcll(bal & ((1ull << lane) - 1ull));
          int slot = lcount + rank;
          if (slot < SEG_CAP) {
            uint2 e; e.x = q * 4u + (unsigned)c; e.y = __float_as_uint(lv);
            seg[slot] = e;
          }
        }
        lcount += __popcll(bal);
      }
    }
  }
#pragma unroll
  for (int o = 32; o > 0; o >>= 1) lsum += __shfl_xor(lsum, o);
  if (lane == 0) {
    wave_count[wid] = (lcount < SEG_CAP) ? lcount : SEG_CAP;
    atomicAdd(&lossAcc[wid & 1023], lsum);
  }
}

// ---- dot: one wave per masked entry; fp32 dot of two Xmol rows -------------
__global__ void dot_kernel(const uint2* __restrict__ entries,
                           const int* __restrict__ wave_count,
                           const float* __restrict__ Xm,
                           float* __restrict__ pred,
                           float* __restrict__ lossAcc) {
  int lane = threadIdx.x & 63;
  int wid = (blockIdx.x * 256 + threadIdx.x) >> 6;
  const int nw = (1024 * 256) >> 6;   // 4096 waves
  int half = lane >> 5;
  int l5 = lane & 31;
  float corr = 0.0f;
  for (int s = wid; s < NSEG; s += nw) {
    int cnt = wave_count[s];
    const uint2* seg = entries + (size_t)s * SEG_CAP;
    for (int k = 0; k < cnt; ++k) {
      uint2 e = seg[k];
      unsigned idx = e.x;
      unsigned i = idx / 8000u;
      unsigned j = idx - i * 8000u;
      unsigned row = half ? j : i;
      f32x4 v = *reinterpret_cast<const f32x4*>(Xm + (size_t)row * 128 + l5 * 4);
      f32x4 o;
      o.x = __shfl_xor(v.x, 32);
      o.y = __shfl_xor(v.y, 32);
      o.z = __shfl_xor(v.z, 32);
      o.w = __shfl_xor(v.w, 32);
      float p = v.x * o.x + v.y * o.y + v.z * o.z + v.w * o.w;
#pragma unroll
      for (int t = 16; t > 0; t >>= 1) p += __shfl_xor(p, t);
      if (lane == 0) {
        pred[idx] = p;
        float lv = __uint_as_float(e.y);
        corr += p * p - 2.0f * p * lv;
      }
    }
  }
  if (lane == 0 && corr != 0.0f) atomicAdd(&lossAcc[wid & 1023], corr);
}

__global__ void loss_final_kernel(const float* __restrict__ lossAcc, float* __restrict__ out0) {
  int t = threadIdx.x;   // 1024
  float v = lossAcc[t];
#pragma unroll
  for (int o = 32; o > 0; o >>= 1) v += __shfl_xor(v, o);
  __shared__ float red[16];
  if ((t & 63) == 0) red[t >> 6] = v;
  __syncthreads();
  if (t == 0) {
    float s = 0;
    for (int i = 0; i < 16; ++i) s += red[i];
    out0[0] = s * (1.0f / ((float)N_NODES * (float)N_NODES));
  }
}

extern "C" void kernel_launch(void* const* d_in, const int* in_sizes, int n_in,
                              void* d_out, int out_size, void* d_ws, size_t ws_size,
                              hipStream_t stream) {
  const float* X      = (const float*)d_in[0];
  const int*   pe     = (const int*)d_in[1];
  const int*   ne     = (const int*)d_in[2];
  const float* labels = (const float*)d_in[3];
  const float* mask   = (const float*)d_in[4];
  const float* Wpb    = (const float*)d_in[5];
  const float* bpb    = (const float*)d_in[6];
  const float* Wnb    = (const float*)d_in[7];
  const float* bnb    = (const float*)d_in[8];
  const float* Wpd    = (const float*)d_in[9];
  const float* bpd    = (const float*)d_in[10];
  const float* Wnd    = (const float*)d_in[11];
  const float* bnd    = (const float*)d_in[12];

  float* out      = (float*)d_out;
  float* out_xmol = out + 1;
  float* out_pred = out + 1 + (size_t)N_NODES * 128;

  char* ws = (char*)d_ws;
  size_t off = 0;
  float* Y = (float*)(ws + off);             off += (size_t)N_NODES * 256 * 4;
  float* H1 = (float*)(ws + off);            off += (size_t)N_NODES * 128 * 4;
  float* XmolWS = (float*)(ws + off);        off += (size_t)N_NODES * 128 * 4;
  unsigned short* WT = (unsigned short*)(ws + off);  off += (size_t)256 * 2048 * 2;
  uint2* entries = (uint2*)(ws + off);       off += (size_t)NSEG * SEG_CAP * 8;
  int* wave_count = (int*)(ws + off);        off += (size_t)NSEG * 4;
  int* rpP  = (int*)(ws + off);              off += 8192 * 4;
  int* rpN  = (int*)(ws + off);              off += 8192 * 4;
  int* colP = (int*)(ws + off);              off += (size_t)NE * 4;
  int* colN = (int*)(ws + off);              off += (size_t)NE * 4;
  char* zstart = ws + off;
  int* cntPi = (int*)(ws + off);             off += (size_t)N_NODES * 4;
  int* cntNi = (int*)(ws + off);             off += (size_t)N_NODES * 4;
  int* curP  = (int*)(ws + off);             off += (size_t)N_NODES * 4;
  int* curN  = (int*)(ws + off);             off += (size_t)N_NODES * 4;
  float* lossAcc = (float*)(ws + off);       off += 1024 * 4;
  size_t zsize = (size_t)((ws + off) - zstart);

  (void)hipMemsetAsync(zstart, 0, zsize, stream);
  packw_kernel<<<2048, 256, 0, stream>>>(Wpb, Wnb, WT);
  gemm1_kernel<<<500, 256, 0, stream>>>(X, WT, Y);
  count_kernel<<<(2 * NE + 255) / 256, 256, 0, stream>>>(pe, ne, cntPi, cntNi);
  scan_kernel<<<2, 1024, 0, stream>>>(cntPi, cntNi, rpP, rpN);
  fill_kernel<<<(2 * NE + 255) / 256, 256, 0, stream>>>(pe, ne, rpP, rpN, curP, curN, colP, colN);
  base_kernel<<<N_NODES, 128, 0, stream>>>(Y, rpP, colP, rpN, colN, bpb, bnb, H1);
  deep_kernel<<<N_NODES, 128, 0, stream>>>(H1, rpP, colP, rpN, colN, Wpd, bpd, Wnd, bnd,
                                           out_xmol, XmolWS);
  mask_scan_kernel<<<SCAN_BLOCKS, 256, 0, stream>>>(mask, labels, out_pred,
                                                    entries, wave_count, lossAcc);
  dot_kernel<<<1024, 256, 0, stream>>>(entries, wave_count, XmolWS, out_pred, lossAcc);
  loss_final_kernel<<<1, 1024, 0, stream>>>(lossAcc, out);
}

// Round 11
// 487.560 us; speedup vs baseline: 1.1395x; 1.1395x over previous
//
#include <hip/hip_runtime.h>
#include <hip/hip_bf16.h>

#define N_NODES 8000
#define D_IN    2048
#define NE      100000
#define NQUADS  16000000          // N_NODES*N_NODES/4
#define SCAN_BLOCKS 2048
#define NSEG    8192              // SCAN_BLOCKS*256/64 waves
#define SEG_CAP 240

typedef __attribute__((ext_vector_type(8))) short bf16x8;
typedef __attribute__((ext_vector_type(4))) float f32x4;

__device__ inline unsigned short f2bf(float f) {
  union { float f; unsigned u; } v; v.f = f;
  unsigned r = v.u + 0x7fffu + ((v.u >> 16) & 1u);   // round-to-nearest-even
  return (unsigned short)(r >> 16);
}

// ---- pack W_pb/W_nb into transposed bf16 [256 cols][2048 k] ---------------
__global__ void packw_kernel(const float* __restrict__ Wpb,
                             const float* __restrict__ Wnb,
                             unsigned short* __restrict__ WT) {
  int idx = blockIdx.x * 256 + threadIdx.x;   // = c*2048 + k
  int c = idx >> 11;
  int k = idx & 2047;
  const float* W = (c < 128) ? Wpb : Wnb;
  int cc = c & 63;
  int kk = (c & 64) ? (2048 + k) : k;
  WT[idx] = f2bf(W[(size_t)kk * 64 + cc]);
}

// ---- GEMM1 (fused cast, 2-deep A prefetch): Y = bf16(X) @ Wpack -----------
__global__ void gemm1_kernel(const float* __restrict__ X,
                             const unsigned short* __restrict__ WT,
                             float* __restrict__ Y) {
  int wave = threadIdx.x >> 6;
  int lane = threadIdx.x & 63;
  int lrow = lane & 15;
  int koff = (lane >> 4) * 8;
  int row = blockIdx.x * 16 + lrow;
  int col0 = wave * 64;
  f32x4 acc[4] = {};
  const float* Ap = X + (size_t)row * D_IN + koff;
  const unsigned short* Bp = WT + (size_t)(col0 + lrow) * D_IN + koff;
  f32x4 a0 = *reinterpret_cast<const f32x4*>(Ap);
  f32x4 a1 = *reinterpret_cast<const f32x4*>(Ap + 4);
  for (int k0 = 0; k0 < D_IN; k0 += 32) {
    f32x4 n0, n1;
    if (k0 + 32 < D_IN) {
      n0 = *reinterpret_cast<const f32x4*>(Ap + k0 + 32);
      n1 = *reinterpret_cast<const f32x4*>(Ap + k0 + 36);
    }
    bf16x8 af;
    af[0] = (short)f2bf(a0.x); af[1] = (short)f2bf(a0.y);
    af[2] = (short)f2bf(a0.z); af[3] = (short)f2bf(a0.w);
    af[4] = (short)f2bf(a1.x); af[5] = (short)f2bf(a1.y);
    af[6] = (short)f2bf(a1.z); af[7] = (short)f2bf(a1.w);
#pragma unroll
    for (int c = 0; c < 4; ++c) {
      bf16x8 b = *reinterpret_cast<const bf16x8*>(Bp + (size_t)c * 16 * D_IN + k0);
      acc[c] = __builtin_amdgcn_mfma_f32_16x16x32_bf16(af, b, acc[c], 0, 0, 0);
    }
    a0 = n0; a1 = n1;
  }
  int crow = blockIdx.x * 16 + (lane >> 4) * 4;
  int ccol = col0 + (lane & 15);
#pragma unroll
  for (int c = 0; c < 4; ++c)
#pragma unroll
    for (int r = 0; r < 4; ++r)
      Y[(size_t)(crow + r) * 256 + ccol + c * 16] = acc[c][r];
}

// ---- CSR build: count -> scan -> fill -------------------------------------
__global__ void count_kernel(const int* __restrict__ pe, const int* __restrict__ ne,
                             int* __restrict__ cntP, int* __restrict__ cntN) {
  int e = blockIdx.x * 256 + threadIdx.x;
  if (e < NE) atomicAdd(&cntP[pe[e]], 1);
  else if (e < 2 * NE) atomicAdd(&cntN[ne[e - NE]], 1);
}

__global__ void scan_kernel(const int* __restrict__ cntP, const int* __restrict__ cntN,
                            int* __restrict__ rpP, int* __restrict__ rpN) {
  const int* cnt = blockIdx.x ? cntN : cntP;
  int* rp = blockIdx.x ? rpN : rpP;
  __shared__ int s[1024];
  int t = threadIdx.x;
  int base = t * 8;
  int loc[8]; int tot = 0;
#pragma unroll
  for (int i = 0; i < 8; ++i) {
    int v = (base + i < N_NODES) ? cnt[base + i] : 0;
    loc[i] = tot; tot += v;
  }
  s[t] = tot; __syncthreads();
  for (int off = 1; off < 1024; off <<= 1) {
    int v = (t >= off) ? s[t - off] : 0;
    __syncthreads();
    s[t] += v;
    __syncthreads();
  }
  int pre = t ? s[t - 1] : 0;
#pragma unroll
  for (int i = 0; i < 8; ++i) {
    int idx = base + i;
    if (idx <= N_NODES) rp[idx] = pre + loc[i];
  }
}

__global__ void fill_kernel(const int* __restrict__ pe, const int* __restrict__ ne,
                            const int* __restrict__ rpP, const int* __restrict__ rpN,
                            int* __restrict__ curP, int* __restrict__ curN,
                            int* __restrict__ colP, int* __restrict__ colN) {
  int e = blockIdx.x * 256 + threadIdx.x;
  if (e < NE) {
    int r = pe[e];
    int pos = atomicAdd(&curP[r], 1);
    colP[rpP[r] + pos] = pe[NE + e];
  } else if (e < 2 * NE) {
    int ee = e - NE;
    int r = ne[ee];
    int pos = atomicAdd(&curN[r], 1);
    colN[rpN[r] + pos] = ne[NE + ee];
  }
}

// ---- base (pull): mean-agg + self + bias, l2norm, tanh -> H1 ---------------
__global__ void base_kernel(const float* __restrict__ Y,
                            const int* __restrict__ rpP, const int* __restrict__ colP,
                            const int* __restrict__ rpN, const int* __restrict__ colN,
                            const float* __restrict__ bpb, const float* __restrict__ bnb,
                            float* __restrict__ H1) {
  int n = blockIdx.x;
  int w = threadIdx.x >> 6;   // 0 = pos, 1 = neg
  int d = threadIdx.x & 63;
  const int* rp = w ? rpN : rpP;
  const int* ci = w ? colN : colP;
  int s0 = rp[n], e0 = rp[n + 1];
  int off = w ? 128 : 0;
  float sum = 0.0f;
  for (int i = s0; i < e0; ++i) sum += Y[(size_t)ci[i] * 256 + off + d];
  float pre = sum / fmaxf((float)(e0 - s0), 1.0f)
            + Y[(size_t)n * 256 + off + 64 + d] + (w ? bnb : bpb)[d];
  float ss = pre * pre;
#pragma unroll
  for (int o = 32; o > 0; o >>= 1) ss += __shfl_xor(ss, o);
  H1[(size_t)n * 128 + w * 64 + d] = tanhf(pre / fmaxf(sqrtf(ss), 1e-12f));
}

// ---- deep (pull): mean-agg + GEMV + l2norm + tanh + final norm -------------
__global__ void deep_kernel(const float* __restrict__ H1,
                            const int* __restrict__ rpP, const int* __restrict__ colP,
                            const int* __restrict__ rpN, const int* __restrict__ colN,
                            const float* __restrict__ Wpd, const float* __restrict__ bpd,
                            const float* __restrict__ Wnd, const float* __restrict__ bnd,
                            float* __restrict__ Xmol, float* __restrict__ XmolWS) {
  int n = blockIdx.x;
  int t = threadIdx.x;          // 0..127 ; wave0 computes h_pos2, wave1 h_neg2
  int w = t >> 6;
  int lane = t & 63;
  __shared__ float sh_op[128], sh_on[128], sh_h[128], sh_ss[2];
  int sP = rpP[n], eP = rpP[n + 1];
  int sN = rpN[n], eN = rpN[n + 1];
  float sp = 0.0f, sn = 0.0f;
  for (int i = sP; i < eP; ++i) sp += H1[(size_t)colP[i] * 128 + t];
  for (int i = sN; i < eN; ++i) sn += H1[(size_t)colN[i] * 128 + t];
  float hv = H1[(size_t)n * 128 + t];
  sh_h[t]  = hv;
  sh_op[t] = (sp + hv) / (float)(eP - sP + 1);   // mean incl. self-loop
  sh_on[t] = (sn + hv) / (float)(eN - sN + 1);
  __syncthreads();
  const float* W = w ? Wnd : Wpd;
  float pre = (w ? bnd : bpd)[lane];
  int o1b = w ? 64 : 0;
  int o2b = w ? 0 : 64;
  for (int k = 0; k < 64; ++k) pre += sh_op[o1b + k] * W[k * 64 + lane];
  for (int k = 0; k < 64; ++k) pre += sh_on[o2b + k] * W[(64 + k) * 64 + lane];
  for (int k = 0; k < 64; ++k) pre += sh_h[w * 64 + k] * W[(128 + k) * 64 + lane];
  float ss = pre * pre;
#pragma unroll
  for (int o = 32; o > 0; o >>= 1) ss += __shfl_xor(ss, o);
  float tv = tanhf(pre / fmaxf(sqrtf(ss), 1e-12f));
  float ts = tv * tv;
#pragma unroll
  for (int o = 32; o > 0; o >>= 1) ts += __shfl_xor(ts, o);
  if (lane == 0) sh_ss[w] = ts;
  __syncthreads();
  float xm = tv / fmaxf(sqrtf(sh_ss[0] + sh_ss[1]), 1e-12f);
  Xmol[(size_t)n * 128 + t] = xm;
  XmolWS[(size_t)n * 128 + t] = xm;
}

// ---- mask_scan: pair-unrolled stream; compact hits into per-wave segments --
__global__ void mask_scan_kernel(const float* __restrict__ mask,
                                 const float* __restrict__ labels,
                                 float* __restrict__ pred,
                                 uint2* __restrict__ entries,
                                 int* __restrict__ wave_count,
                                 float* __restrict__ lossAcc) {
  int tid = blockIdx.x * 256 + threadIdx.x;
  int lane = threadIdx.x & 63;
  int wid = tid >> 6;
  uint2* seg = entries + (size_t)wid * SEG_CAP;
  int lcount = 0;
  float lsum = 0.0f;
  const unsigned stride = SCAN_BLOCKS * 256;
  f32x4 zero4 = {0.0f, 0.0f, 0.0f, 0.0f};
  for (unsigned q0 = tid; q0 < NQUADS; q0 += 2 * stride) {
    unsigned q1 = q0 + stride;
    bool has1 = q1 < NQUADS;            // wave-uniform (boundary 64-aligned)
    f32x4 m0 = *reinterpret_cast<const f32x4*>(mask + (size_t)q0 * 4);
    f32x4 l0 = *reinterpret_cast<const f32x4*>(labels + (size_t)q0 * 4);
    f32x4 m1, l1;
    if (has1) {
      m1 = *reinterpret_cast<const f32x4*>(mask + (size_t)q1 * 4);
      l1 = *reinterpret_cast<const f32x4*>(labels + (size_t)q1 * 4);
    }
    *reinterpret_cast<f32x4*>(pred + (size_t)q0 * 4) = zero4;
    if (has1) *reinterpret_cast<f32x4*>(pred + (size_t)q1 * 4) = zero4;
#pragma unroll
    for (int half = 0; half < 2; ++half) {
      if (half == 1 && !has1) break;
      f32x4 m = half ? m1 : m0;
      f32x4 l = half ? l1 : l0;
      unsigned q = half ? q1 : q0;
      lsum += l.x * l.x + l.y * l.y + l.z * l.z + l.w * l.w;
#pragma unroll
      for (int c = 0; c < 4; ++c) {
        float mv = (c == 0) ? m.x : (c == 1) ? m.y : (c == 2) ? m.z : m.w;
        float lv = (c == 0) ? l.x : (c == 1) ? l.y : (c == 2) ? l.z : l.w;
        unsigned long long bal = __ballot(mv != 0.0f);
        if (bal) {
          if (mv != 0.0f) {
            int rank = __popcll(bal & ((1ull << lane) - 1ull));
            int slot = lcount + rank;
            if (slot < SEG_CAP) {
              uint2 e; e.x = q * 4u + (unsigned)c; e.y = __float_as_uint(lv);
              seg[slot] = e;
            }
          }
          lcount += __popcll(bal);
        }
      }
    }
  }
#pragma unroll
  for (int o = 32; o > 0; o >>= 1) lsum += __shfl_xor(lsum, o);
  if (lane == 0) {
    wave_count[wid] = (lcount < SEG_CAP) ? lcount : SEG_CAP;
    atomicAdd(&lossAcc[wid & 1023], lsum);
  }
}

// ---- dot v2: thread-per-entry; full-unrolled in-thread 128-dot -------------
__global__ void dot_kernel(const uint2* __restrict__ entries,
                           const int* __restrict__ wave_count,
                           const float* __restrict__ Xm,
                           float* __restrict__ pred,
                           float* __restrict__ lossAcc) {
  int wv = threadIdx.x >> 6;
  int lane = threadIdx.x & 63;
  int seg_id = blockIdx.x * 4 + wv;         // 2048 blocks * 4 waves = NSEG
  int cnt = wave_count[seg_id];
  const uint2* seg = entries + (size_t)seg_id * SEG_CAP;
  float corr = 0.0f;
  for (int k = lane; k < cnt; k += 64) {
    uint2 e = seg[k];
    unsigned idx = e.x;
    unsigned i = idx / 8000u;
    unsigned j = idx - i * 8000u;
    const f32x4* A = reinterpret_cast<const f32x4*>(Xm + (size_t)i * 128);
    const f32x4* B = reinterpret_cast<const f32x4*>(Xm + (size_t)j * 128);
    float p0 = 0, p1 = 0, p2 = 0, p3 = 0;
#pragma unroll
    for (int kk = 0; kk < 32; kk += 4) {
      f32x4 a0 = A[kk], a1 = A[kk + 1], a2 = A[kk + 2], a3 = A[kk + 3];
      f32x4 b0 = B[kk], b1 = B[kk + 1], b2 = B[kk + 2], b3 = B[kk + 3];
      p0 += a0.x * b0.x + a0.y * b0.y + a0.z * b0.z + a0.w * b0.w;
      p1 += a1.x * b1.x + a1.y * b1.y + a1.z * b1.z + a1.w * b1.w;
      p2 += a2.x * b2.x + a2.y * b2.y + a2.z * b2.z + a2.w * b2.w;
      p3 += a3.x * b3.x + a3.y * b3.y + a3.z * b3.z + a3.w * b3.w;
    }
    float p = (p0 + p1) + (p2 + p3);
    pred[idx] = p;
    float lv = __uint_as_float(e.y);
    corr += p * p - 2.0f * p * lv;
  }
#pragma unroll
  for (int o = 32; o > 0; o >>= 1) corr += __shfl_xor(corr, o);
  if (lane == 0 && corr != 0.0f) atomicAdd(&lossAcc[seg_id & 1023], corr);
}

__global__ void loss_final_kernel(const float* __restrict__ lossAcc, float* __restrict__ out0) {
  int t = threadIdx.x;   // 1024
  float v = lossAcc[t];
#pragma unroll
  for (int o = 32; o > 0; o >>= 1) v += __shfl_xor(v, o);
  __shared__ float red[16];
  if ((t & 63) == 0) red[t >> 6] = v;
  __syncthreads();
  if (t == 0) {
    float s = 0;
    for (int i = 0; i < 16; ++i) s += red[i];
    out0[0] = s * (1.0f / ((float)N_NODES * (float)N_NODES));
  }
}

extern "C" void kernel_launch(void* const* d_in, const int* in_sizes, int n_in,
                              void* d_out, int out_size, void* d_ws, size_t ws_size,
                              hipStream_t stream) {
  const float* X      = (const float*)d_in[0];
  const int*   pe     = (const int*)d_in[1];
  const int*   ne     = (const int*)d_in[2];
  const float* labels = (const float*)d_in[3];
  const float* mask   = (const float*)d_in[4];
  const float* Wpb    = (const float*)d_in[5];
  const float* bpb    = (const float*)d_in[6];
  const float* Wnb    = (const float*)d_in[7];
  const float* bnb    = (const float*)d_in[8];
  const float* Wpd    = (const float*)d_in[9];
  const float* bpd    = (const float*)d_in[10];
  const float* Wnd    = (const float*)d_in[11];
  const float* bnd    = (const float*)d_in[12];

  float* out      = (float*)d_out;
  float* out_xmol = out + 1;
  float* out_pred = out + 1 + (size_t)N_NODES * 128;

  char* ws = (char*)d_ws;
  size_t off = 0;
  float* Y = (float*)(ws + off);             off += (size_t)N_NODES * 256 * 4;
  float* H1 = (float*)(ws + off);            off += (size_t)N_NODES * 128 * 4;
  float* XmolWS = (float*)(ws + off);        off += (size_t)N_NODES * 128 * 4;
  unsigned short* WT = (unsigned short*)(ws + off);  off += (size_t)256 * 2048 * 2;
  uint2* entries = (uint2*)(ws + off);       off += (size_t)NSEG * SEG_CAP * 8;
  int* wave_count = (int*)(ws + off);        off += (size_t)NSEG * 4;
  int* rpP  = (int*)(ws + off);              off += 8192 * 4;
  int* rpN  = (int*)(ws + off);              off += 8192 * 4;
  int* colP = (int*)(ws + off);              off += (size_t)NE * 4;
  int* colN = (int*)(ws + off);              off += (size_t)NE * 4;
  char* zstart = ws + off;
  int* cntPi = (int*)(ws + off);             off += (size_t)N_NODES * 4;
  int* cntNi = (int*)(ws + off);             off += (size_t)N_NODES * 4;
  int* curP  = (int*)(ws + off);             off += (size_t)N_NODES * 4;
  int* curN  = (int*)(ws + off);             off += (size_t)N_NODES * 4;
  float* lossAcc = (float*)(ws + off);       off += 1024 * 4;
  size_t zsize = (size_t)((ws + off) - zstart);

  (void)hipMemsetAsync(zstart, 0, zsize, stream);
  packw_kernel<<<2048, 256, 0, stream>>>(Wpb, Wnb, WT);
  gemm1_kernel<<<500, 256, 0, stream>>>(X, WT, Y);
  count_kernel<<<(2 * NE + 255) / 256, 256, 0, stream>>>(pe, ne, cntPi, cntNi);
  scan_kernel<<<2, 1024, 0, stream>>>(cntPi, cntNi, rpP, rpN);
  fill_kernel<<<(2 * NE + 255) / 256, 256, 0, stream>>>(pe, ne, rpP, rpN, curP, curN, colP, colN);
  base_kernel<<<N_NODES, 128, 0, stream>>>(Y, rpP, colP, rpN, colN, bpb, bnb, H1);
  deep_kernel<<<N_NODES, 128, 0, stream>>>(H1, rpP, colP, rpN, colN, Wpd, bpd, Wnd, bnd,
                                           out_xmol, XmolWS);
  mask_scan_kernel<<<SCAN_BLOCKS, 256, 0, stream>>>(mask, labels, out_pred,
                                                    entries, wave_count, lossAcc);
  dot_kernel<<<NSEG / 4, 256, 0, stream>>>(entries, wave_count, XmolWS, out_pred, lossAcc);
  loss_final_kernel<<<1, 1024, 0, stream>>>(lossAcc, out);
}

// Round 12
// 449.657 us; speedup vs baseline: 1.2355x; 1.0843x over previous
//
#include <hip/hip_runtime.h>
#include <hip/hip_bf16.h>

#define N_NODES 8000
#define D_IN    2048
#define NE      100000
#define NQUADS  16000000u         // N*N/4
#define SEG_CAP 112
#define NSEG_CH 8192              // 2048 scan blocks * 4 waves
#define G_GEMM  500
#define G_FILL  782
#define G_SCAN  2048
#define G_NODE2 4000
#define CH0_LO 0u
#define CH0_HI 5333376u
#define CH1_LO 5333376u
#define CH1_HI 10666752u
#define CH2_LO 10666752u
#define CH2_HI 16000000u

typedef __attribute__((ext_vector_type(8))) short bf16x8;
typedef __attribute__((ext_vector_type(4))) float f32x4;

__device__ inline unsigned short f2bf(float f) {
  union { float f; unsigned u; } v; v.f = f;
  unsigned r = v.u + 0x7fffu + ((v.u >> 16) & 1u);
  return (unsigned short)(r >> 16);
}

// ======================= device bodies =======================

__device__ void packw_body(int b, const float* __restrict__ Wpb,
                           const float* __restrict__ Wnb,
                           unsigned short* __restrict__ WT) {
  int idx = b * 256 + threadIdx.x;
  int c = idx >> 11;
  int k = idx & 2047;
  const float* W = (c < 128) ? Wpb : Wnb;
  int cc = c & 63;
  int kk = (c & 64) ? (2048 + k) : k;
  WT[idx] = f2bf(W[(size_t)kk * 64 + cc]);
}

__device__ void count_body(int b, const int* __restrict__ pe, const int* __restrict__ ne,
                           int* __restrict__ cntP, int* __restrict__ cntN) {
  int e = b * 256 + threadIdx.x;
  if (e < NE) atomicAdd(&cntP[pe[e]], 1);
  else if (e < 2 * NE) atomicAdd(&cntN[ne[e - NE]], 1);
}

__device__ void gemm1_body(int b, const float* __restrict__ X,
                           const unsigned short* __restrict__ WT,
                           float* __restrict__ Y) {
  int wave = threadIdx.x >> 6;
  int lane = threadIdx.x & 63;
  int lrow = lane & 15;
  int koff = (lane >> 4) * 8;
  int row = b * 16 + lrow;
  int col0 = wave * 64;
  f32x4 acc[4] = {};
  const float* Ap = X + (size_t)row * D_IN + koff;
  const unsigned short* Bp = WT + (size_t)(col0 + lrow) * D_IN + koff;
  f32x4 a0 = *reinterpret_cast<const f32x4*>(Ap);
  f32x4 a1 = *reinterpret_cast<const f32x4*>(Ap + 4);
  for (int k0 = 0; k0 < D_IN; k0 += 32) {
    f32x4 n0 = a0, n1 = a1;
    if (k0 + 32 < D_IN) {
      n0 = *reinterpret_cast<const f32x4*>(Ap + k0 + 32);
      n1 = *reinterpret_cast<const f32x4*>(Ap + k0 + 36);
    }
    bf16x8 af;
    af[0] = (short)f2bf(a0.x); af[1] = (short)f2bf(a0.y);
    af[2] = (short)f2bf(a0.z); af[3] = (short)f2bf(a0.w);
    af[4] = (short)f2bf(a1.x); af[5] = (short)f2bf(a1.y);
    af[6] = (short)f2bf(a1.z); af[7] = (short)f2bf(a1.w);
#pragma unroll
    for (int c = 0; c < 4; ++c) {
      bf16x8 bfr = *reinterpret_cast<const bf16x8*>(Bp + (size_t)c * 16 * D_IN + k0);
      acc[c] = __builtin_amdgcn_mfma_f32_16x16x32_bf16(af, bfr, acc[c], 0, 0, 0);
    }
    a0 = n0; a1 = n1;
  }
  int crow = b * 16 + (lane >> 4) * 4;
  int ccol = col0 + (lane & 15);
#pragma unroll
  for (int c = 0; c < 4; ++c)
#pragma unroll
    for (int r = 0; r < 4; ++r)
      Y[(size_t)(crow + r) * 256 + ccol + c * 16] = acc[c][r];
}

__device__ void fill_body(int b, const int* __restrict__ pe, const int* __restrict__ ne,
                          const int* __restrict__ rpP, const int* __restrict__ rpN,
                          int* __restrict__ curP, int* __restrict__ curN,
                          int* __restrict__ colP, int* __restrict__ colN) {
  int e = b * 256 + threadIdx.x;
  if (e < NE) {
    int r = pe[e];
    int pos = atomicAdd(&curP[r], 1);
    colP[rpP[r] + pos] = pe[NE + e];
  } else if (e < 2 * NE) {
    int ee = e - NE;
    int r = ne[ee];
    int pos = atomicAdd(&curN[r], 1);
    colN[rpN[r] + pos] = ne[NE + ee];
  }
}

// grid-stride masked-compact scan over quad range [lo,hi)
__device__ void scan_body(int sb, int chunk, unsigned lo, unsigned hi,
                          const float* __restrict__ mask,
                          const float* __restrict__ labels,
                          float* __restrict__ pred,
                          uint2* __restrict__ entries,
                          int* __restrict__ wave_count,
                          float* __restrict__ lossAcc) {
  int tid = sb * 256 + threadIdx.x;
  int lane = threadIdx.x & 63;
  int wid = chunk * NSEG_CH + (tid >> 6);
  uint2* seg = entries + (size_t)wid * SEG_CAP;
  int lcount = 0;
  float lsum = 0.0f;
  const unsigned stride = G_SCAN * 256;
  f32x4 zero4 = {0.0f, 0.0f, 0.0f, 0.0f};
  for (unsigned q = lo + tid; q < hi; q += stride) {
    f32x4 m = *reinterpret_cast<const f32x4*>(mask + (size_t)q * 4);
    f32x4 l = *reinterpret_cast<const f32x4*>(labels + (size_t)q * 4);
    *reinterpret_cast<f32x4*>(pred + (size_t)q * 4) = zero4;
    lsum += l.x * l.x + l.y * l.y + l.z * l.z + l.w * l.w;
#pragma unroll
    for (int c = 0; c < 4; ++c) {
      float mv = (c == 0) ? m.x : (c == 1) ? m.y : (c == 2) ? m.z : m.w;
      float lv = (c == 0) ? l.x : (c == 1) ? l.y : (c == 2) ? l.z : l.w;
      unsigned long long bal = __ballot(mv != 0.0f);
      if (bal) {
        if (mv != 0.0f) {
          int rank = __popcll(bal & ((1ull << lane) - 1ull));
          int slot = lcount + rank;
          if (slot < SEG_CAP) {
            uint2 e; e.x = q * 4u + (unsigned)c; e.y = __float_as_uint(lv);
            seg[slot] = e;
          }
        }
        lcount += __popcll(bal);
      }
    }
  }
#pragma unroll
  for (int o = 32; o > 0; o >>= 1) lsum += __shfl_xor(lsum, o);
  if (lane == 0) {
    wave_count[wid] = (lcount < SEG_CAP) ? lcount : SEG_CAP;
    atomicAdd(&lossAcc[wid & 1023], lsum);
  }
}

// base, 2 nodes per 256-thread block
__device__ void base2_body(int b, const float* __restrict__ Y,
                           const int* __restrict__ rpP, const int* __restrict__ colP,
                           const int* __restrict__ rpN, const int* __restrict__ colN,
                           const float* __restrict__ bpb, const float* __restrict__ bnb,
                           float* __restrict__ H1) {
  int n = b * 2 + (threadIdx.x >> 7);
  int tt = threadIdx.x & 127;
  int w = tt >> 6;
  int d = tt & 63;
  const int* rp = w ? rpN : rpP;
  const int* ci = w ? colN : colP;
  int s0 = rp[n], e0 = rp[n + 1];
  int off = w ? 128 : 0;
  float sum = 0.0f;
  for (int i = s0; i < e0; ++i) sum += Y[(size_t)ci[i] * 256 + off + d];
  float pre = sum / fmaxf((float)(e0 - s0), 1.0f)
            + Y[(size_t)n * 256 + off + 64 + d] + (w ? bnb : bpb)[d];
  float ss = pre * pre;
#pragma unroll
  for (int o = 32; o > 0; o >>= 1) ss += __shfl_xor(ss, o);
  H1[(size_t)n * 128 + tt] = tanhf(pre / fmaxf(sqrtf(ss), 1e-12f));
}

// deep, 2 nodes per 256-thread block (duplicated shared arrays)
__device__ void deep2_body(int b, const float* __restrict__ H1,
                           const int* __restrict__ rpP, const int* __restrict__ colP,
                           const int* __restrict__ rpN, const int* __restrict__ colN,
                           const float* __restrict__ Wpd, const float* __restrict__ bpd,
                           const float* __restrict__ Wnd, const float* __restrict__ bnd,
                           float* __restrict__ Xmol, float* __restrict__ XmolWS) {
  __shared__ float sh_op[2][128], sh_on[2][128], sh_h[2][128], sh_ss[2][2];
  int half = threadIdx.x >> 7;
  int n = b * 2 + half;
  int tt = threadIdx.x & 127;
  int w = tt >> 6;
  int lane = tt & 63;
  int sP = rpP[n], eP = rpP[n + 1];
  int sN = rpN[n], eN = rpN[n + 1];
  float sp = 0.0f, sn = 0.0f;
  for (int i = sP; i < eP; ++i) sp += H1[(size_t)colP[i] * 128 + tt];
  for (int i = sN; i < eN; ++i) sn += H1[(size_t)colN[i] * 128 + tt];
  float hv = H1[(size_t)n * 128 + tt];
  sh_h[half][tt]  = hv;
  sh_op[half][tt] = (sp + hv) / (float)(eP - sP + 1);
  sh_on[half][tt] = (sn + hv) / (float)(eN - sN + 1);
  __syncthreads();
  const float* W = w ? Wnd : Wpd;
  float pre = (w ? bnd : bpd)[lane];
  int o1b = w ? 64 : 0;
  int o2b = w ? 0 : 64;
  for (int k = 0; k < 64; ++k) pre += sh_op[half][o1b + k] * W[k * 64 + lane];
  for (int k = 0; k < 64; ++k) pre += sh_on[half][o2b + k] * W[(64 + k) * 64 + lane];
  for (int k = 0; k < 64; ++k) pre += sh_h[half][w * 64 + k] * W[(128 + k) * 64 + lane];
  float ss = pre * pre;
#pragma unroll
  for (int o = 32; o > 0; o >>= 1) ss += __shfl_xor(ss, o);
  float tv = tanhf(pre / fmaxf(sqrtf(ss), 1e-12f));
  float ts = tv * tv;
#pragma unroll
  for (int o = 32; o > 0; o >>= 1) ts += __shfl_xor(ts, o);
  if (lane == 0) sh_ss[half][w] = ts;
  __syncthreads();
  float xm = tv / fmaxf(sqrtf(sh_ss[half][0] + sh_ss[half][1]), 1e-12f);
  Xmol[(size_t)n * 128 + tt] = xm;
  XmolWS[(size_t)n * 128 + tt] = xm;
}

// ======================= kernels =======================

__global__ void prep_kernel(const float* __restrict__ Wpb, const float* __restrict__ Wnb,
                            unsigned short* __restrict__ WT,
                            const int* __restrict__ pe, const int* __restrict__ ne,
                            int* __restrict__ cntP, int* __restrict__ cntN) {
  if (blockIdx.x < 2048) packw_body(blockIdx.x, Wpb, Wnb, WT);
  else count_body(blockIdx.x - 2048, pe, ne, cntP, cntN);
}

__global__ void scan_kernel(const int* __restrict__ cntP, const int* __restrict__ cntN,
                            int* __restrict__ rpP, int* __restrict__ rpN) {
  const int* cnt = blockIdx.x ? cntN : cntP;
  int* rp = blockIdx.x ? rpN : rpP;
  __shared__ int s[1024];
  int t = threadIdx.x;
  int base = t * 8;
  int loc[8]; int tot = 0;
#pragma unroll
  for (int i = 0; i < 8; ++i) {
    int v = (base + i < N_NODES) ? cnt[base + i] : 0;
    loc[i] = tot; tot += v;
  }
  s[t] = tot; __syncthreads();
  for (int off = 1; off < 1024; off <<= 1) {
    int v = (t >= off) ? s[t - off] : 0;
    __syncthreads();
    s[t] += v;
    __syncthreads();
  }
  int pre = t ? s[t - 1] : 0;
#pragma unroll
  for (int i = 0; i < 8; ++i) {
    int idx = base + i;
    if (idx <= N_NODES) rp[idx] = pre + loc[i];
  }
}

__global__ void fused1_kernel(const float* __restrict__ X,
                              const unsigned short* __restrict__ WT,
                              float* __restrict__ Y,
                              const int* __restrict__ pe, const int* __restrict__ ne,
                              const int* __restrict__ rpP, const int* __restrict__ rpN,
                              int* __restrict__ curP, int* __restrict__ curN,
                              int* __restrict__ colP, int* __restrict__ colN,
                              const float* __restrict__ mask, const float* __restrict__ labels,
                              float* __restrict__ pred, uint2* __restrict__ entries,
                              int* __restrict__ wave_count, float* __restrict__ lossAcc) {
  if (blockIdx.x < G_GEMM)
    gemm1_body(blockIdx.x, X, WT, Y);
  else if (blockIdx.x < G_GEMM + G_FILL)
    fill_body(blockIdx.x - G_GEMM, pe, ne, rpP, rpN, curP, curN, colP, colN);
  else
    scan_body(blockIdx.x - G_GEMM - G_FILL, 0, CH0_LO, CH0_HI,
              mask, labels, pred, entries, wave_count, lossAcc);
}

__global__ void fused2_kernel(const float* __restrict__ Y,
                              const int* __restrict__ rpP, const int* __restrict__ colP,
                              const int* __restrict__ rpN, const int* __restrict__ colN,
                              const float* __restrict__ bpb, const float* __restrict__ bnb,
                              float* __restrict__ H1,
                              const float* __restrict__ mask, const float* __restrict__ labels,
                              float* __restrict__ pred, uint2* __restrict__ entries,
                              int* __restrict__ wave_count, float* __restrict__ lossAcc) {
  if (blockIdx.x < G_NODE2)
    base2_body(blockIdx.x, Y, rpP, colP, rpN, colN, bpb, bnb, H1);
  else
    scan_body(blockIdx.x - G_NODE2, 1, CH1_LO, CH1_HI,
              mask, labels, pred, entries, wave_count, lossAcc);
}

__global__ void fused3_kernel(const float* __restrict__ H1,
                              const int* __restrict__ rpP, const int* __restrict__ colP,
                              const int* __restrict__ rpN, const int* __restrict__ colN,
                              const float* __restrict__ Wpd, const float* __restrict__ bpd,
                              const float* __restrict__ Wnd, const float* __restrict__ bnd,
                              float* __restrict__ Xmol, float* __restrict__ XmolWS,
                              const float* __restrict__ mask, const float* __restrict__ labels,
                              float* __restrict__ pred, uint2* __restrict__ entries,
                              int* __restrict__ wave_count, float* __restrict__ lossAcc) {
  if (blockIdx.x < G_NODE2)
    deep2_body(blockIdx.x, H1, rpP, colP, rpN, colN, Wpd, bpd, Wnd, bnd, Xmol, XmolWS);
  else
    scan_body(blockIdx.x - G_NODE2, 2, CH2_LO, CH2_HI,
              mask, labels, pred, entries, wave_count, lossAcc);
}

__global__ void dot_kernel(const uint2* __restrict__ entries,
                           const int* __restrict__ wave_count,
                           const float* __restrict__ Xm,
                           float* __restrict__ pred,
                           float* __restrict__ lossAcc) {
  int wv = threadIdx.x >> 6;
  int lane = threadIdx.x & 63;
  int seg_id = blockIdx.x * 4 + wv;
  int cnt = wave_count[seg_id];
  const uint2* seg = entries + (size_t)seg_id * SEG_CAP;
  float corr = 0.0f;
  for (int k = lane; k < cnt; k += 64) {
    uint2 e = seg[k];
    unsigned idx = e.x;
    unsigned i = idx / 8000u;
    unsigned j = idx - i * 8000u;
    const f32x4* A = reinterpret_cast<const f32x4*>(Xm + (size_t)i * 128);
    const f32x4* B = reinterpret_cast<const f32x4*>(Xm + (size_t)j * 128);
    float p0 = 0, p1 = 0, p2 = 0, p3 = 0;
#pragma unroll
    for (int kk = 0; kk < 32; kk += 4) {
      f32x4 a0 = A[kk], a1 = A[kk + 1], a2 = A[kk + 2], a3 = A[kk + 3];
      f32x4 b0 = B[kk], b1 = B[kk + 1], b2 = B[kk + 2], b3 = B[kk + 3];
      p0 += a0.x * b0.x + a0.y * b0.y + a0.z * b0.z + a0.w * b0.w;
      p1 += a1.x * b1.x + a1.y * b1.y + a1.z * b1.z + a1.w * b1.w;
      p2 += a2.x * b2.x + a2.y * b2.y + a2.z * b2.z + a2.w * b2.w;
      p3 += a3.x * b3.x + a3.y * b3.y + a3.z * b3.z + a3.w * b3.w;
    }
    float p = (p0 + p1) + (p2 + p3);
    pred[idx] = p;
    float lv = __uint_as_float(e.y);
    corr += p * p - 2.0f * p * lv;
  }
#pragma unroll
  for (int o = 32; o > 0; o >>= 1) corr += __shfl_xor(corr, o);
  if (lane == 0 && corr != 0.0f) atomicAdd(&lossAcc[seg_id & 1023], corr);
}

__global__ void loss_final_kernel(const float* __restrict__ lossAcc, float* __restrict__ out0) {
  int t = threadIdx.x;   // 1024
  float v = lossAcc[t];
#pragma unroll
  for (int o = 32; o > 0; o >>= 1) v += __shfl_xor(v, o);
  __shared__ float red[16];
  if ((t & 63) == 0) red[t >> 6] = v;
  __syncthreads();
  if (t == 0) {
    float s = 0;
    for (int i = 0; i < 16; ++i) s += red[i];
    out0[0] = s * (1.0f / ((float)N_NODES * (float)N_NODES));
  }
}

extern "C" void kernel_launch(void* const* d_in, const int* in_sizes, int n_in,
                              void* d_out, int out_size, void* d_ws, size_t ws_size,
                              hipStream_t stream) {
  const float* X      = (const float*)d_in[0];
  const int*   pe     = (const int*)d_in[1];
  const int*   ne     = (const int*)d_in[2];
  const float* labels = (const float*)d_in[3];
  const float* mask   = (const float*)d_in[4];
  const float* Wpb    = (const float*)d_in[5];
  const float* bpb    = (const float*)d_in[6];
  const float* Wnb    = (const float*)d_in[7];
  const float* bnb    = (const float*)d_in[8];
  const float* Wpd    = (const float*)d_in[9];
  const float* bpd    = (const float*)d_in[10];
  const float* Wnd    = (const float*)d_in[11];
  const float* bnd    = (const float*)d_in[12];

  float* out      = (float*)d_out;
  float* out_xmol = out + 1;
  float* out_pred = out + 1 + (size_t)N_NODES * 128;

  char* ws = (char*)d_ws;
  size_t off = 0;
  float* Y = (float*)(ws + off);             off += (size_t)N_NODES * 256 * 4;
  float* H1 = (float*)(ws + off);            off += (size_t)N_NODES * 128 * 4;
  float* XmolWS = (float*)(ws + off);        off += (size_t)N_NODES * 128 * 4;
  unsigned short* WT = (unsigned short*)(ws + off);  off += (size_t)256 * 2048 * 2;
  uint2* entries = (uint2*)(ws + off);       off += (size_t)3 * NSEG_CH * SEG_CAP * 8;
  int* wave_count = (int*)(ws + off);        off += (size_t)3 * NSEG_CH * 4;
  int* rpP  = (int*)(ws + off);              off += 8192 * 4;
  int* rpN  = (int*)(ws + off);              off += 8192 * 4;
  int* colP = (int*)(ws + off);              off += (size_t)NE * 4;
  int* colN = (int*)(ws + off);              off += (size_t)NE * 4;
  char* zstart = ws + off;
  int* cntPi = (int*)(ws + off);             off += (size_t)N_NODES * 4;
  int* cntNi = (int*)(ws + off);             off += (size_t)N_NODES * 4;
  int* curP  = (int*)(ws + off);             off += (size_t)N_NODES * 4;
  int* curN  = (int*)(ws + off);             off += (size_t)N_NODES * 4;
  float* lossAcc = (float*)(ws + off);       off += 1024 * 4;
  size_t zsize = (size_t)((ws + off) - zstart);

  (void)hipMemsetAsync(zstart, 0, zsize, stream);
  prep_kernel<<<2048 + 782, 256, 0, stream>>>(Wpb, Wnb, WT, pe, ne, cntPi, cntNi);
  scan_kernel<<<2, 1024, 0, stream>>>(cntPi, cntNi, rpP, rpN);
  fused1_kernel<<<G_GEMM + G_FILL + G_SCAN, 256, 0, stream>>>(
      X, WT, Y, pe, ne, rpP, rpN, curP, curN, colP, colN,
      mask, labels, out_pred, entries, wave_count, lossAcc);
  fused2_kernel<<<G_NODE2 + G_SCAN, 256, 0, stream>>>(
      Y, rpP, colP, rpN, colN, bpb, bnb, H1,
      mask, labels, out_pred, entries, wave_count, lossAcc);
  fused3_kernel<<<G_NODE2 + G_SCAN, 256, 0, stream>>>(
      H1, rpP, colP, rpN, colN, Wpd, bpd, Wnd, bnd, out_xmol, XmolWS,
      mask, labels, out_pred, entries, wave_count, lossAcc);
  dot_kernel<<<3 * NSEG_CH / 4, 256, 0, stream>>>(entries, wave_count, XmolWS,
                                                  out_pred, lossAcc);
  loss_final_kernel<<<1, 1024, 0, stream>>>(lossAcc, out);
}